// Round 4
// baseline (239.621 us; speedup 1.0000x reference)
//
#include <hip/hip_runtime.h>

// FlashCRA on MI355X — round 4:
//  - attention: split-KV within block (valid because no-max softmax partials are additive),
//    QBLK=64, grid 1024 (4 blocks/CU), single-buffer LDS pair + T14 async reg-staging,
//    LDS combine of partials.
//  - rest unchanged from round 3.

typedef __bf16 bf16;
typedef __bf16 bf16x8 __attribute__((ext_vector_type(8)));
typedef __bf16 bf16x4 __attribute__((ext_vector_type(4)));
typedef float f32x4 __attribute__((ext_vector_type(4)));
typedef float f32x16 __attribute__((ext_vector_type(16)));
typedef unsigned int u32;
typedef u32 u32x4 __attribute__((ext_vector_type(4)));

__device__ __forceinline__ bf16 f2bf(float f) {
  unsigned u = __builtin_bit_cast(unsigned, f);
  u += 0x7FFFu + ((u >> 16) & 1u);            // RNE, inputs finite
  unsigned short h = (unsigned short)(u >> 16);
  return __builtin_bit_cast(bf16, h);
}

__device__ __forceinline__ void gload_lds16(const bf16* g, bf16* l) {
  __builtin_amdgcn_global_load_lds((const __attribute__((address_space(1))) u32*)(const void*)g,
                                   (__attribute__((address_space(3))) u32*)(void*)l, 16, 0, 0);
}

__device__ __forceinline__ u32 cvtpk_bf16(float lo, float hi) {
  u32 r;
  asm("v_cvt_pk_bf16_f32 %0, %1, %2" : "=v"(r) : "v"(lo), "v"(hi));
  return r;
}
__device__ __forceinline__ void perm32swap(u32& a, u32& b) {
  asm("v_permlane32_swap_b32 %0, %1" : "+v"(a), "+v"(b));
}

#if __has_builtin(__builtin_amdgcn_exp2f)
#define EXP2(x) __builtin_amdgcn_exp2f(x)
#else
#define EXP2(x) exp2f(x)
#endif

// SCALE * log2(e), folded into Q at pack time
#define QSCALE 0.18033688f

// ---------------- fp32 -> bf16 elementwise ----------------
__global__ __launch_bounds__(256) void k_convert(const float* __restrict__ in,
                                                 bf16* __restrict__ out, int n4) {
  int i = blockIdx.x * 256 + threadIdx.x;
  if (i >= n4) return;
  const float4 v = ((const float4*)in)[i];
  bf16x4 o;
  o[0] = f2bf(v.x); o[1] = f2bf(v.y); o[2] = f2bf(v.z); o[3] = f2bf(v.w);
  *(bf16x4*)(out + (size_t)i * 4) = o;
}

// ---------------- fp32 [R][C] -> bf16 [C][R] ----------------
__global__ __launch_bounds__(256) void k_transpose(const float* __restrict__ in,
                                                   bf16* __restrict__ out, int R, int C) {
  __shared__ float t[64][65];
  int c0 = blockIdx.x * 64, r0 = blockIdx.y * 64;
  for (int e = threadIdx.x; e < 4096; e += 256) {
    int r = e >> 6, c = e & 63;
    t[r][c] = in[(size_t)(r0 + r) * C + c0 + c];
  }
  __syncthreads();
  for (int e = threadIdx.x; e < 4096; e += 256) {
    int c = e >> 6, r = e & 63;
    out[(size_t)(c0 + c) * R + r0 + r] = f2bf(t[r][c]);
  }
}

// ---------------- generic C[M][N] = A @ Bt^T + bias (m97 structure) ----------------
__global__ __launch_bounds__(256) void k_gemm128(const bf16* __restrict__ A,
                                                 const bf16* __restrict__ Bt,
                                                 const float* __restrict__ bias,
                                                 float* __restrict__ C,
                                                 int M, int N, int K) {
  __shared__ bf16 sA[128 * 64];
  __shared__ bf16 sB[128 * 64];
  const int tid = threadIdx.x;
  const int lane = tid & 63, w = tid >> 6;
  const int lrow = lane & 15, lgrp = lane >> 4;
  const int wm = (w >> 1) * 64, wn = (w & 1) * 64;
  const int m0 = blockIdx.x * 128, n0 = blockIdx.y * 128;
  const int srow = tid >> 3, sslot = (tid & 7) * 8;

  f32x4 acc[4][4] = {};

  for (int k0 = 0; k0 < K; k0 += 64) {
#pragma unroll
    for (int i = 0; i < 4; ++i) {
      gload_lds16(A  + (size_t)(m0 + i * 32 + srow) * K + k0 + sslot, &sA[i * 2048 + w * 512]);
      gload_lds16(Bt + (size_t)(n0 + i * 32 + srow) * K + k0 + sslot, &sB[i * 2048 + w * 512]);
    }
    __syncthreads();
#pragma unroll
    for (int kk = 0; kk < 2; ++kk) {
      bf16x8 af[4], bff[4];
#pragma unroll
      for (int mi = 0; mi < 4; ++mi)
        af[mi] = *(const bf16x8*)&sA[(wm + mi * 16 + lrow) * 64 + kk * 32 + lgrp * 8];
#pragma unroll
      for (int ni = 0; ni < 4; ++ni)
        bff[ni] = *(const bf16x8*)&sB[(wn + ni * 16 + lrow) * 64 + kk * 32 + lgrp * 8];
      __builtin_amdgcn_s_setprio(1);
#pragma unroll
      for (int mi = 0; mi < 4; ++mi)
#pragma unroll
        for (int ni = 0; ni < 4; ++ni)
          acc[mi][ni] = __builtin_amdgcn_mfma_f32_16x16x32_bf16(af[mi], bff[ni], acc[mi][ni], 0, 0, 0);
      __builtin_amdgcn_s_setprio(0);
    }
    __syncthreads();
  }
#pragma unroll
  for (int mi = 0; mi < 4; ++mi)
#pragma unroll
    for (int ni = 0; ni < 4; ++ni) {
      const int col = n0 + wn + ni * 16 + lrow;
      const float bv = bias ? bias[col] : 0.f;
#pragma unroll
      for (int j = 0; j < 4; ++j) {
        const int row = m0 + wm + mi * 16 + lgrp * 4 + j;
        C[(size_t)row * N + col] = acc[mi][ni][j] + bv;
      }
    }
}

// ---------------- QKV GEMM with fused bias + rotation + pack epilogue ----------------
__global__ __launch_bounds__(256) void k_gemm_qkv(const bf16* __restrict__ A,
                                                  const bf16* __restrict__ Bt,
                                                  const float* __restrict__ bqkv,
                                                  const float* __restrict__ phases,
                                                  bf16* __restrict__ qb,
                                                  bf16* __restrict__ kb,
                                                  bf16* __restrict__ vb) {
  __shared__ bf16 sA[128 * 64];
  __shared__ bf16 sB[128 * 64];
  const int tid = threadIdx.x;
  const int lane = tid & 63, w = tid >> 6;
  const int lrow = lane & 15, lgrp = lane >> 4;
  const int wm = (w >> 1) * 64, wn = (w & 1) * 64;
  const int m0 = blockIdx.x * 128, n0 = blockIdx.y * 128;
  const int srow = tid >> 3, sslot = (tid & 7) * 8;
  const int K = 1024;

  f32x4 acc[4][4] = {};

  for (int k0 = 0; k0 < K; k0 += 64) {
#pragma unroll
    for (int i = 0; i < 4; ++i) {
      gload_lds16(A  + (size_t)(m0 + i * 32 + srow) * K + k0 + sslot, &sA[i * 2048 + w * 512]);
      gload_lds16(Bt + (size_t)(n0 + i * 32 + srow) * K + k0 + sslot, &sB[i * 2048 + w * 512]);
    }
    __syncthreads();
#pragma unroll
    for (int kk = 0; kk < 2; ++kk) {
      bf16x8 af[4], bff[4];
#pragma unroll
      for (int mi = 0; mi < 4; ++mi)
        af[mi] = *(const bf16x8*)&sA[(wm + mi * 16 + lrow) * 64 + kk * 32 + lgrp * 8];
#pragma unroll
      for (int ni = 0; ni < 4; ++ni)
        bff[ni] = *(const bf16x8*)&sB[(wn + ni * 16 + lrow) * 64 + kk * 32 + lgrp * 8];
      __builtin_amdgcn_s_setprio(1);
#pragma unroll
      for (int mi = 0; mi < 4; ++mi)
#pragma unroll
        for (int ni = 0; ni < 4; ++ni)
          acc[mi][ni] = __builtin_amdgcn_mfma_f32_16x16x32_bf16(af[mi], bff[ni], acc[mi][ni], 0, 0, 0);
      __builtin_amdgcn_s_setprio(0);
    }
    __syncthreads();
  }

  // ---- epilogue ----
  const int sec = n0 >> 10;          // 0=q, 1=k, 2=v
  const int nn = n0 & 1023;
  const int hh = (nn + wn) >> 6;     // head for this wave
  const float b0 = bqkv[n0 + wn + lrow];
  const float b1 = bqkv[n0 + wn + 16 + lrow];
  const float b2 = bqkv[n0 + wn + 32 + lrow];
  const float b3 = bqkv[n0 + wn + 48 + lrow];

  if (sec == 2) {
#pragma unroll
    for (int mi = 0; mi < 4; ++mi) {
      const int row0 = m0 + wm + mi * 16 + lgrp * 4;
      const int b = row0 >> 11, l0 = row0 & 2047;
#pragma unroll
      for (int ni = 0; ni < 4; ++ni) {
        const int d = ni * 16 + lrow;
        const float bv = (ni == 0) ? b0 : (ni == 1) ? b1 : (ni == 2) ? b2 : b3;
        bf16x4 pv;
#pragma unroll
        for (int j = 0; j < 4; ++j) pv[j] = f2bf(acc[mi][ni][j] + bv);
        *(bf16x4*)&vb[(((size_t)(b * 16 + hh)) * 64 + d) * 2048 + l0] = pv;
      }
    }
  } else {
    bf16* qk = sec ? kb : qb;
    const float qs = sec ? 1.0f : QSCALE;
#pragma unroll
    for (int mi = 0; mi < 4; ++mi) {
#pragma unroll
      for (int j = 0; j < 4; ++j) {
        const int row = m0 + wm + mi * 16 + lgrp * 4 + j;
        const int b = row >> 11, l = row & 2047;
        const float ph1 = phases[(size_t)row * 512 + hh * 32 + lrow];
        const float ph2 = phases[(size_t)row * 512 + hh * 32 + 16 + lrow];
        float s1, c1, s2, c2;
        __sincosf(ph1, &s1, &c1);
        __sincosf(ph2, &s2, &c2);
        const float t0 = acc[mi][0][j] + b0;
        const float t1 = acc[mi][1][j] + b1;
        const float t2 = acc[mi][2][j] + b2;
        const float t3 = acc[mi][3][j] + b3;
        bf16* base = qk + (((size_t)(b * 16 + hh)) * 2048 + l) * 64;
        base[lrow]      = f2bf((t0 * c1 - t2 * s1) * qs);
        base[16 + lrow] = f2bf((t1 * c2 - t3 * s2) * qs);
        base[32 + lrow] = f2bf((t0 * s1 + t2 * c1) * qs);
        base[48 + lrow] = f2bf((t1 * s2 + t3 * c2) * qs);
      }
    }
  }
}

// ---------------- flash attention, round 4: split-KV within block ----------------
// Block = 4 waves, QBLK=64. Waves {0,1}: q-halves, even KV tiles (tsel=0);
// waves {2,3}: same q-halves, odd KV tiles (tsel=1). Single-buffered LDS holds a
// PAIR of 64x64 tiles for K and V^T; next pair reg-staged during compute (T14).
// Partials combined through LDS at the end (no-max softmax => additive).
__global__ __launch_bounds__(256, 4) void k_flash_attn4(const bf16* __restrict__ qb,
                                                        const bf16* __restrict__ kb,
                                                        const bf16* __restrict__ vb,
                                                        bf16* __restrict__ attnout) {
  const int tid = threadIdx.x, lane = tid & 63, w = tid >> 6;
  const int ql = lane & 31, hi = lane >> 5;
  const int tsel = w >> 1;                    // KV parity this wave computes
  const int qh = w & 1;                       // q-half (32 rows)
  // XCD-aware swizzle over 1024 blocks: 128 consecutive nids per XCD
  const int fid = blockIdx.x;
  const int nid = (fid & 7) * 128 + (fid >> 3);
  const int qblk = nid & 31, h = (nid >> 5) & 15, b = nid >> 9;
  const size_t bh = (size_t)b * 16 + h;
  const bf16* Kp = kb + bh * 2048 * 64;
  const bf16* Vp = vb + bh * 64 * 2048;

  __shared__ bf16 sK[2][64 * 64];             // [tile parity][row*64 + col], XOR-swizzled
  __shared__ bf16 sV[2][64 * 64];

  const bf16* Qp = qb + (bh * 2048 + (size_t)qblk * 64 + qh * 32 + ql) * 64;
  bf16x8 qf[4];
#pragma unroll
  for (int c = 0; c < 4; ++c) qf[c] = *(const bf16x8*)(Qp + c * 16 + hi * 8);

  // staging: thread owns rows srow, srow+32 at 16B slot `slot` for each of 4 sub-tiles
  const int srow = tid >> 3;                  // 0..31
  const int slot = tid & 7;
  const int ps = (slot ^ (srow & 7)) * 8;     // swizzled LDS slot (rows r and r+32 share r&7)

  u32x4 rg[8];
#define ISSUE(P)                                                                \
  do {                                                                          \
    const int kv0 = (P) * 128;                                                  \
    rg[0] = *(const u32x4*)(Kp + (size_t)(kv0 + srow) * 64 + slot * 8);         \
    rg[1] = *(const u32x4*)(Kp + (size_t)(kv0 + srow + 32) * 64 + slot * 8);    \
    rg[2] = *(const u32x4*)(Kp + (size_t)(kv0 + 64 + srow) * 64 + slot * 8);    \
    rg[3] = *(const u32x4*)(Kp + (size_t)(kv0 + 96 + srow) * 64 + slot * 8);    \
    rg[4] = *(const u32x4*)(Vp + (size_t)srow * 2048 + kv0 + slot * 8);         \
    rg[5] = *(const u32x4*)(Vp + (size_t)(srow + 32) * 2048 + kv0 + slot * 8);  \
    rg[6] = *(const u32x4*)(Vp + (size_t)srow * 2048 + kv0 + 64 + slot * 8);    \
    rg[7] = *(const u32x4*)(Vp + (size_t)(srow + 32) * 2048 + kv0 + 64 + slot * 8); \
  } while (0)
#define WRITE()                                                \
  do {                                                         \
    *(u32x4*)&sK[0][srow * 64 + ps]        = rg[0];            \
    *(u32x4*)&sK[0][(srow + 32) * 64 + ps] = rg[1];            \
    *(u32x4*)&sK[1][srow * 64 + ps]        = rg[2];            \
    *(u32x4*)&sK[1][(srow + 32) * 64 + ps] = rg[3];            \
    *(u32x4*)&sV[0][srow * 64 + ps]        = rg[4];            \
    *(u32x4*)&sV[0][(srow + 32) * 64 + ps] = rg[5];            \
    *(u32x4*)&sV[1][srow * 64 + ps]        = rg[6];            \
    *(u32x4*)&sV[1][(srow + 32) * 64 + ps] = rg[7];            \
  } while (0)

  f32x16 o0 = {}, o1 = {};
  float lsum = 0.f;

  ISSUE(0);
  WRITE();
  __syncthreads();

  const bf16* sKc = &sK[tsel][0];
  const bf16* sVc = &sV[tsel][0];

  for (int p = 0; p < 16; ++p) {
    if (p < 15) ISSUE(p + 1);

    // ---- QK^T on this wave's tile ----
    f32x16 st0 = {}, st1 = {};
#pragma unroll
    for (int c = 0; c < 4; ++c) {
      const int j = (c * 2 + hi) ^ (ql & 7);
      bf16x8 kf0 = *(const bf16x8*)&sKc[ql * 64 + j * 8];
      bf16x8 kf1 = *(const bf16x8*)&sKc[(32 + ql) * 64 + j * 8];
      __builtin_amdgcn_s_setprio(1);
      st0 = __builtin_amdgcn_mfma_f32_32x32x16_bf16(kf0, qf[c], st0, 0, 0, 0);
      st1 = __builtin_amdgcn_mfma_f32_32x32x16_bf16(kf1, qf[c], st1, 0, 0, 0);
      __builtin_amdgcn_s_setprio(0);
    }

    // ---- no-max softmax: P = exp2(S) ----
    float rs = 0.f;
#pragma unroll
    for (int j2 = 0; j2 < 16; ++j2) {
      float pv = EXP2(st0[j2]);
      st0[j2] = pv; rs += pv;
    }
#pragma unroll
    for (int j2 = 0; j2 < 16; ++j2) {
      float pv = EXP2(st1[j2]);
      st1[j2] = pv; rs += pv;
    }
    rs += __shfl_xor(rs, 32);
    lsum += rs;

    // ---- P -> bf16, PV ----
#pragma unroll
    for (int s = 0; s < 2; ++s) {
#pragma unroll
      for (int h2 = 0; h2 < 2; ++h2) {
        u32 a0, a1, a2, a3;
        if (s == 0) {
          a0 = cvtpk_bf16(st0[h2 * 8 + 0], st0[h2 * 8 + 1]);
          a1 = cvtpk_bf16(st0[h2 * 8 + 2], st0[h2 * 8 + 3]);
          a2 = cvtpk_bf16(st0[h2 * 8 + 4], st0[h2 * 8 + 5]);
          a3 = cvtpk_bf16(st0[h2 * 8 + 6], st0[h2 * 8 + 7]);
        } else {
          a0 = cvtpk_bf16(st1[h2 * 8 + 0], st1[h2 * 8 + 1]);
          a1 = cvtpk_bf16(st1[h2 * 8 + 2], st1[h2 * 8 + 3]);
          a2 = cvtpk_bf16(st1[h2 * 8 + 4], st1[h2 * 8 + 5]);
          a3 = cvtpk_bf16(st1[h2 * 8 + 6], st1[h2 * 8 + 7]);
        }
        perm32swap(a0, a2);
        perm32swap(a1, a3);
        union { u32 u[4]; bf16x8 v; } cu;
        cu.u[0] = a0; cu.u[1] = a1; cu.u[2] = a2; cu.u[3] = a3;
        const int c = s * 2 + h2;
        const int j = (c * 2 + hi) ^ (ql & 7);
        bf16x8 vf0 = *(const bf16x8*)&sVc[ql * 64 + j * 8];
        bf16x8 vf1 = *(const bf16x8*)&sVc[(32 + ql) * 64 + j * 8];
        __builtin_amdgcn_s_setprio(1);
        o0 = __builtin_amdgcn_mfma_f32_32x32x16_bf16(vf0, cu.v, o0, 0, 0, 0);
        o1 = __builtin_amdgcn_mfma_f32_32x32x16_bf16(vf1, cu.v, o1, 0, 0, 0);
        __builtin_amdgcn_s_setprio(0);
      }
    }
    __syncthreads();                 // all waves done reading this pair
    if (p < 15) {
      WRITE();                       // compiler inserts vmcnt waits on rg deps
      __syncthreads();               // pair ready
    }
  }

  // ---- combine partials across KV parities (waves w and w+2 share q-rows) ----
  float* cb = (float*)&sK[0][0];     // 2*64*34*4B = 17.4KB, fits in sK+sV region
  if (w >= 2) {
    const int idx = ((w - 2) * 64 + lane) * 34;
#pragma unroll
    for (int i = 0; i < 16; ++i) cb[idx + i] = o0[i];
#pragma unroll
    for (int i = 0; i < 16; ++i) cb[idx + 16 + i] = o1[i];
    cb[idx + 32] = lsum;
  }
  __syncthreads();
  if (w < 2) {
    const int idx = (w * 64 + lane) * 34;
#pragma unroll
    for (int i = 0; i < 16; ++i) o0[i] += cb[idx + i];
#pragma unroll
    for (int i = 0; i < 16; ++i) o1[i] += cb[idx + 16 + i];
    lsum += cb[idx + 32];

    const float inv = 1.f / lsum;
    const int qrow = qblk * 64 + qh * 32 + ql;
    bf16* outp = attnout + ((size_t)b * 2048 + qrow) * 1024 + h * 64;
#pragma unroll
    for (int j2 = 0; j2 < 4; ++j2) {
      bf16x4 ov;
#pragma unroll
      for (int jj = 0; jj < 4; ++jj) ov[jj] = f2bf(o0[j2 * 4 + jj] * inv);
      *(bf16x4*)(outp + j2 * 8 + hi * 4) = ov;
#pragma unroll
      for (int jj = 0; jj < 4; ++jj) ov[jj] = f2bf(o1[j2 * 4 + jj] * inv);
      *(bf16x4*)(outp + 32 + j2 * 8 + hi * 4) = ov;
    }
  }
#undef ISSUE
#undef WRITE
}

// ---------------- launch ----------------
extern "C" void kernel_launch(void* const* d_in, const int* in_sizes, int n_in,
                              void* d_out, int out_size, void* d_ws, size_t ws_size,
                              hipStream_t stream) {
  (void)in_sizes; (void)n_in; (void)out_size; (void)ws_size;
  const float* x    = (const float*)d_in[0];
  const float* p    = (const float*)d_in[1];
  const float* Wqkv = (const float*)d_in[2];
  const float* bqkv = (const float*)d_in[3];
  const float* Wout = (const float*)d_in[4];
  const float* bout = (const float*)d_in[5];
  const float* proj = (const float*)d_in[6];
  float* out = (float*)d_out;

  char* ws = (char*)d_ws;
  size_t off = 0;
  bf16* xb     = (bf16*)(ws + off); off += (size_t)4096 * 1024 * 2;
  bf16* pb     = (bf16*)(ws + off); off += (size_t)4096 * 1024 * 2;
  bf16* WqkvT  = (bf16*)(ws + off); off += (size_t)3072 * 1024 * 2;
  bf16* projT  = (bf16*)(ws + off); off += (size_t)512  * 1024 * 2;
  bf16* WoutT  = (bf16*)(ws + off); off += (size_t)1024 * 1024 * 2;
  float* phases= (float*)(ws + off); off += (size_t)4096 * 512 * 4;
  bf16* qb     = (bf16*)(ws + off); off += (size_t)4096 * 1024 * 2;
  bf16* kb     = (bf16*)(ws + off); off += (size_t)4096 * 1024 * 2;
  bf16* vb     = (bf16*)(ws + off); off += (size_t)4096 * 1024 * 2;
  bf16* attnb  = (bf16*)(ws + off); off += (size_t)4096 * 1024 * 2;

  k_convert<<<4096, 256, 0, stream>>>(x, xb, 1048576);
  k_convert<<<4096, 256, 0, stream>>>(p, pb, 1048576);
  k_transpose<<<dim3(48, 16), 256, 0, stream>>>(Wqkv, WqkvT, 1024, 3072);
  k_transpose<<<dim3(8, 16),  256, 0, stream>>>(proj, projT, 1024, 512);
  k_transpose<<<dim3(16, 16), 256, 0, stream>>>(Wout, WoutT, 1024, 1024);

  k_gemm128<<<dim3(32, 4), 256, 0, stream>>>(pb, projT, nullptr, phases, 4096, 512, 1024);
  k_gemm_qkv<<<dim3(32, 24), 256, 0, stream>>>(xb, WqkvT, bqkv, phases, qb, kb, vb);

  k_flash_attn4<<<1024, 256, 0, stream>>>(qb, kb, vb, attnb);

  k_gemm128<<<dim3(32, 8), 256, 0, stream>>>(attnb, WoutT, bout, out, 4096, 1024, 1024);
}

// Round 5
// 175.193 us; speedup vs baseline: 1.3678x; 1.3678x over previous
//
#include <hip/hip_runtime.h>

// FlashCRA on MI355X — round 5:
//  - attention: QBLK=64, 4 waves split the KV tile rows (0-31 / 32-63), grid 1024
//    (4 blocks/CU), round-3 gload_lds double-buffered staging (NO reg staging -> no spill),
//    LDS combine of additive partials (no-max softmax).
//  - GEMMs unchanged from round 3/4.

typedef __bf16 bf16;
typedef __bf16 bf16x8 __attribute__((ext_vector_type(8)));
typedef __bf16 bf16x4 __attribute__((ext_vector_type(4)));
typedef float f32x4 __attribute__((ext_vector_type(4)));
typedef float f32x16 __attribute__((ext_vector_type(16)));
typedef unsigned int u32;

__device__ __forceinline__ bf16 f2bf(float f) {
  unsigned u = __builtin_bit_cast(unsigned, f);
  u += 0x7FFFu + ((u >> 16) & 1u);            // RNE, inputs finite
  unsigned short h = (unsigned short)(u >> 16);
  return __builtin_bit_cast(bf16, h);
}

__device__ __forceinline__ void gload_lds16(const bf16* g, bf16* l) {
  __builtin_amdgcn_global_load_lds((const __attribute__((address_space(1))) u32*)(const void*)g,
                                   (__attribute__((address_space(3))) u32*)(void*)l, 16, 0, 0);
}

__device__ __forceinline__ u32 cvtpk_bf16(float lo, float hi) {
  u32 r;
  asm("v_cvt_pk_bf16_f32 %0, %1, %2" : "=v"(r) : "v"(lo), "v"(hi));
  return r;
}
__device__ __forceinline__ void perm32swap(u32& a, u32& b) {
  asm("v_permlane32_swap_b32 %0, %1" : "+v"(a), "+v"(b));
}

#if __has_builtin(__builtin_amdgcn_exp2f)
#define EXP2(x) __builtin_amdgcn_exp2f(x)
#else
#define EXP2(x) exp2f(x)
#endif

// SCALE * log2(e), folded into Q at pack time
#define QSCALE 0.18033688f

// ---------------- fp32 -> bf16 elementwise ----------------
__global__ __launch_bounds__(256) void k_convert(const float* __restrict__ in,
                                                 bf16* __restrict__ out, int n4) {
  int i = blockIdx.x * 256 + threadIdx.x;
  if (i >= n4) return;
  const float4 v = ((const float4*)in)[i];
  bf16x4 o;
  o[0] = f2bf(v.x); o[1] = f2bf(v.y); o[2] = f2bf(v.z); o[3] = f2bf(v.w);
  *(bf16x4*)(out + (size_t)i * 4) = o;
}

// ---------------- fp32 [R][C] -> bf16 [C][R] ----------------
__global__ __launch_bounds__(256) void k_transpose(const float* __restrict__ in,
                                                   bf16* __restrict__ out, int R, int C) {
  __shared__ float t[64][65];
  int c0 = blockIdx.x * 64, r0 = blockIdx.y * 64;
  for (int e = threadIdx.x; e < 4096; e += 256) {
    int r = e >> 6, c = e & 63;
    t[r][c] = in[(size_t)(r0 + r) * C + c0 + c];
  }
  __syncthreads();
  for (int e = threadIdx.x; e < 4096; e += 256) {
    int c = e >> 6, r = e & 63;
    out[(size_t)(c0 + c) * R + r0 + r] = f2bf(t[r][c]);
  }
}

// ---------------- generic C[M][N] = A @ Bt^T + bias (m97 structure) ----------------
__global__ __launch_bounds__(256) void k_gemm128(const bf16* __restrict__ A,
                                                 const bf16* __restrict__ Bt,
                                                 const float* __restrict__ bias,
                                                 float* __restrict__ C,
                                                 int M, int N, int K) {
  __shared__ bf16 sA[128 * 64];
  __shared__ bf16 sB[128 * 64];
  const int tid = threadIdx.x;
  const int lane = tid & 63, w = tid >> 6;
  const int lrow = lane & 15, lgrp = lane >> 4;
  const int wm = (w >> 1) * 64, wn = (w & 1) * 64;
  const int m0 = blockIdx.x * 128, n0 = blockIdx.y * 128;
  const int srow = tid >> 3, sslot = (tid & 7) * 8;

  f32x4 acc[4][4] = {};

  for (int k0 = 0; k0 < K; k0 += 64) {
#pragma unroll
    for (int i = 0; i < 4; ++i) {
      gload_lds16(A  + (size_t)(m0 + i * 32 + srow) * K + k0 + sslot, &sA[i * 2048 + w * 512]);
      gload_lds16(Bt + (size_t)(n0 + i * 32 + srow) * K + k0 + sslot, &sB[i * 2048 + w * 512]);
    }
    __syncthreads();
#pragma unroll
    for (int kk = 0; kk < 2; ++kk) {
      bf16x8 af[4], bff[4];
#pragma unroll
      for (int mi = 0; mi < 4; ++mi)
        af[mi] = *(const bf16x8*)&sA[(wm + mi * 16 + lrow) * 64 + kk * 32 + lgrp * 8];
#pragma unroll
      for (int ni = 0; ni < 4; ++ni)
        bff[ni] = *(const bf16x8*)&sB[(wn + ni * 16 + lrow) * 64 + kk * 32 + lgrp * 8];
      __builtin_amdgcn_s_setprio(1);
#pragma unroll
      for (int mi = 0; mi < 4; ++mi)
#pragma unroll
        for (int ni = 0; ni < 4; ++ni)
          acc[mi][ni] = __builtin_amdgcn_mfma_f32_16x16x32_bf16(af[mi], bff[ni], acc[mi][ni], 0, 0, 0);
      __builtin_amdgcn_s_setprio(0);
    }
    __syncthreads();
  }
#pragma unroll
  for (int mi = 0; mi < 4; ++mi)
#pragma unroll
    for (int ni = 0; ni < 4; ++ni) {
      const int col = n0 + wn + ni * 16 + lrow;
      const float bv = bias ? bias[col] : 0.f;
#pragma unroll
      for (int j = 0; j < 4; ++j) {
        const int row = m0 + wm + mi * 16 + lgrp * 4 + j;
        C[(size_t)row * N + col] = acc[mi][ni][j] + bv;
      }
    }
}

// ---------------- QKV GEMM with fused bias + rotation + pack epilogue ----------------
__global__ __launch_bounds__(256) void k_gemm_qkv(const bf16* __restrict__ A,
                                                  const bf16* __restrict__ Bt,
                                                  const float* __restrict__ bqkv,
                                                  const float* __restrict__ phases,
                                                  bf16* __restrict__ qb,
                                                  bf16* __restrict__ kb,
                                                  bf16* __restrict__ vb) {
  __shared__ bf16 sA[128 * 64];
  __shared__ bf16 sB[128 * 64];
  const int tid = threadIdx.x;
  const int lane = tid & 63, w = tid >> 6;
  const int lrow = lane & 15, lgrp = lane >> 4;
  const int wm = (w >> 1) * 64, wn = (w & 1) * 64;
  const int m0 = blockIdx.x * 128, n0 = blockIdx.y * 128;
  const int srow = tid >> 3, sslot = (tid & 7) * 8;
  const int K = 1024;

  f32x4 acc[4][4] = {};

  for (int k0 = 0; k0 < K; k0 += 64) {
#pragma unroll
    for (int i = 0; i < 4; ++i) {
      gload_lds16(A  + (size_t)(m0 + i * 32 + srow) * K + k0 + sslot, &sA[i * 2048 + w * 512]);
      gload_lds16(Bt + (size_t)(n0 + i * 32 + srow) * K + k0 + sslot, &sB[i * 2048 + w * 512]);
    }
    __syncthreads();
#pragma unroll
    for (int kk = 0; kk < 2; ++kk) {
      bf16x8 af[4], bff[4];
#pragma unroll
      for (int mi = 0; mi < 4; ++mi)
        af[mi] = *(const bf16x8*)&sA[(wm + mi * 16 + lrow) * 64 + kk * 32 + lgrp * 8];
#pragma unroll
      for (int ni = 0; ni < 4; ++ni)
        bff[ni] = *(const bf16x8*)&sB[(wn + ni * 16 + lrow) * 64 + kk * 32 + lgrp * 8];
      __builtin_amdgcn_s_setprio(1);
#pragma unroll
      for (int mi = 0; mi < 4; ++mi)
#pragma unroll
        for (int ni = 0; ni < 4; ++ni)
          acc[mi][ni] = __builtin_amdgcn_mfma_f32_16x16x32_bf16(af[mi], bff[ni], acc[mi][ni], 0, 0, 0);
      __builtin_amdgcn_s_setprio(0);
    }
    __syncthreads();
  }

  // ---- epilogue ----
  const int sec = n0 >> 10;          // 0=q, 1=k, 2=v
  const int nn = n0 & 1023;
  const int hh = (nn + wn) >> 6;     // head for this wave
  const float b0 = bqkv[n0 + wn + lrow];
  const float b1 = bqkv[n0 + wn + 16 + lrow];
  const float b2 = bqkv[n0 + wn + 32 + lrow];
  const float b3 = bqkv[n0 + wn + 48 + lrow];

  if (sec == 2) {
#pragma unroll
    for (int mi = 0; mi < 4; ++mi) {
      const int row0 = m0 + wm + mi * 16 + lgrp * 4;
      const int b = row0 >> 11, l0 = row0 & 2047;
#pragma unroll
      for (int ni = 0; ni < 4; ++ni) {
        const int d = ni * 16 + lrow;
        const float bv = (ni == 0) ? b0 : (ni == 1) ? b1 : (ni == 2) ? b2 : b3;
        bf16x4 pv;
#pragma unroll
        for (int j = 0; j < 4; ++j) pv[j] = f2bf(acc[mi][ni][j] + bv);
        *(bf16x4*)&vb[(((size_t)(b * 16 + hh)) * 64 + d) * 2048 + l0] = pv;
      }
    }
  } else {
    bf16* qk = sec ? kb : qb;
    const float qs = sec ? 1.0f : QSCALE;
#pragma unroll
    for (int mi = 0; mi < 4; ++mi) {
#pragma unroll
      for (int j = 0; j < 4; ++j) {
        const int row = m0 + wm + mi * 16 + lgrp * 4 + j;
        const int b = row >> 11, l = row & 2047;
        const float ph1 = phases[(size_t)row * 512 + hh * 32 + lrow];
        const float ph2 = phases[(size_t)row * 512 + hh * 32 + 16 + lrow];
        float s1, c1, s2, c2;
        __sincosf(ph1, &s1, &c1);
        __sincosf(ph2, &s2, &c2);
        const float t0 = acc[mi][0][j] + b0;
        const float t1 = acc[mi][1][j] + b1;
        const float t2 = acc[mi][2][j] + b2;
        const float t3 = acc[mi][3][j] + b3;
        bf16* base = qk + (((size_t)(b * 16 + hh)) * 2048 + l) * 64;
        base[lrow]      = f2bf((t0 * c1 - t2 * s1) * qs);
        base[16 + lrow] = f2bf((t1 * c2 - t3 * s2) * qs);
        base[32 + lrow] = f2bf((t0 * s1 + t2 * c1) * qs);
        base[48 + lrow] = f2bf((t1 * s2 + t3 * c2) * qs);
      }
    }
  }
}

// ---------------- flash attention, round 5: QBLK=64, waves split KV-tile rows ----------------
// Block = 4 waves. Waves {0,1}: kv rows 0-31 of each 64-tile; waves {2,3}: rows 32-63.
// qh = w&1 selects the 32-q half. Staging identical to round 3 (gload_lds, dbuf, 32KB).
// Partials additive (no-max softmax) -> LDS combine at end.
__global__ __launch_bounds__(256, 4) void k_flash_attn5(const bf16* __restrict__ qb,
                                                        const bf16* __restrict__ kb,
                                                        const bf16* __restrict__ vb,
                                                        bf16* __restrict__ attnout) {
  const int tid = threadIdx.x, lane = tid & 63, w = tid >> 6;
  const int ql = lane & 31, hi = lane >> 5;
  const int tsel = w >> 1;                    // kv half of tile
  const int qh = w & 1;                       // q half (32 rows)
  // XCD-aware swizzle over 1024 blocks: 128 consecutive nids per XCD (4 heads' K/V = 2MB < L2)
  const int fid = blockIdx.x;
  const int nid = (fid & 7) * 128 + (fid >> 3);
  const int qblk = nid & 31, h = (nid >> 5) & 15, b = nid >> 9;
  const size_t bh = (size_t)b * 16 + h;
  const bf16* Kp = kb + bh * 2048 * 64;
  const bf16* Vp = vb + bh * 64 * 2048;

  __shared__ __align__(16) char smem[32768];
  bf16* sK = (bf16*)smem;                     // [2][64*64] double-buffered
  bf16* sV = (bf16*)(smem + 16384);           // [2][64*64]

  const bf16* Qp = qb + (bh * 2048 + (size_t)qblk * 64 + qh * 32 + ql) * 64;
  bf16x8 qf[4];
#pragma unroll
  for (int c = 0; c < 4; ++c) qf[c] = *(const bf16x8*)(Qp + c * 16 + hi * 8);

  const int srow = tid >> 3;                  // 0..31
  const int swz = (tid & 7) ^ (srow & 7);     // pre-swizzled global 16B slot

  f32x16 o0 = {}, o1 = {};
  float lsum = 0.f;

#define STAGE(BUF, KV0)                                                                       \
  do {                                                                                        \
    gload_lds16(Kp + (size_t)((KV0) + srow) * 64 + swz * 8,        sK + (BUF) * 4096 + w * 512); \
    gload_lds16(Kp + (size_t)((KV0) + srow + 32) * 64 + swz * 8,   sK + (BUF) * 4096 + 2048 + w * 512); \
    gload_lds16(Vp + (size_t)srow * 2048 + (KV0) + swz * 8,        sV + (BUF) * 4096 + w * 512); \
    gload_lds16(Vp + (size_t)(srow + 32) * 2048 + (KV0) + swz * 8, sV + (BUF) * 4096 + 2048 + w * 512); \
  } while (0)

  STAGE(0, 0);
  __syncthreads();

  for (int t = 0; t < 32; ++t) {
    const int cur = t & 1;
    if (t < 31) STAGE(cur ^ 1, (t + 1) * 64);

    const bf16* sKc = sK + cur * 4096;
    const bf16* sVc = sV + cur * 4096;

    // ---- QK^T: S^T[kv = tsel*32 + (reg map)][q = ql] ----
    f32x16 st0 = {};
#pragma unroll
    for (int c = 0; c < 4; ++c) {
      const int j = (c * 2 + hi) ^ (ql & 7);
      bf16x8 kf = *(const bf16x8*)&sKc[(tsel * 32 + ql) * 64 + j * 8];
      __builtin_amdgcn_s_setprio(1);
      st0 = __builtin_amdgcn_mfma_f32_32x32x16_bf16(kf, qf[c], st0, 0, 0, 0);
      __builtin_amdgcn_s_setprio(0);
    }

    // ---- no-max softmax: P = exp2(S) (scale folded into Q) ----
    float rs = 0.f;
#pragma unroll
    for (int j2 = 0; j2 < 16; ++j2) {
      float pv = EXP2(st0[j2]);
      st0[j2] = pv; rs += pv;
    }
    rs += __shfl_xor(rs, 32);
    lsum += rs;

    // ---- P -> bf16 fragments, PV ----
#pragma unroll
    for (int fs = 0; fs < 2; ++fs) {
      u32 a0 = cvtpk_bf16(st0[fs * 8 + 0], st0[fs * 8 + 1]);
      u32 a1 = cvtpk_bf16(st0[fs * 8 + 2], st0[fs * 8 + 3]);
      u32 a2 = cvtpk_bf16(st0[fs * 8 + 4], st0[fs * 8 + 5]);
      u32 a3 = cvtpk_bf16(st0[fs * 8 + 6], st0[fs * 8 + 7]);
      perm32swap(a0, a2);
      perm32swap(a1, a3);
      union { u32 u[4]; bf16x8 v; } cu;
      cu.u[0] = a0; cu.u[1] = a1; cu.u[2] = a2; cu.u[3] = a3;
      const int j = (tsel * 4 + fs * 2 + hi) ^ (ql & 7);
      bf16x8 vf0 = *(const bf16x8*)&sVc[ql * 64 + j * 8];
      bf16x8 vf1 = *(const bf16x8*)&sVc[(32 + ql) * 64 + j * 8];
      __builtin_amdgcn_s_setprio(1);
      o0 = __builtin_amdgcn_mfma_f32_32x32x16_bf16(vf0, cu.v, o0, 0, 0, 0);
      o1 = __builtin_amdgcn_mfma_f32_32x32x16_bf16(vf1, cu.v, o1, 0, 0, 0);
      __builtin_amdgcn_s_setprio(0);
    }
    __syncthreads();
  }

  // ---- combine partials across kv halves (waves w and w+2 share q-rows) ----
  float* cb = (float*)smem;                   // 2*64*34*4B = 17.4KB <= 32KB
  if (w >= 2) {
    const int idx = ((w - 2) * 64 + lane) * 34;
#pragma unroll
    for (int i = 0; i < 16; ++i) cb[idx + i] = o0[i];
#pragma unroll
    for (int i = 0; i < 16; ++i) cb[idx + 16 + i] = o1[i];
    cb[idx + 32] = lsum;
  }
  __syncthreads();
  if (w < 2) {
    const int idx = (w * 64 + lane) * 34;
#pragma unroll
    for (int i = 0; i < 16; ++i) o0[i] += cb[idx + i];
#pragma unroll
    for (int i = 0; i < 16; ++i) o1[i] += cb[idx + 16 + i];
    lsum += cb[idx + 32];

    const float inv = 1.f / lsum;
    const int qrow = qblk * 64 + qh * 32 + ql;
    bf16* outp = attnout + ((size_t)b * 2048 + qrow) * 1024 + h * 64;
#pragma unroll
    for (int j2 = 0; j2 < 4; ++j2) {
      bf16x4 ov;
#pragma unroll
      for (int jj = 0; jj < 4; ++jj) ov[jj] = f2bf(o0[j2 * 4 + jj] * inv);
      *(bf16x4*)(outp + j2 * 8 + hi * 4) = ov;
#pragma unroll
      for (int jj = 0; jj < 4; ++jj) ov[jj] = f2bf(o1[j2 * 4 + jj] * inv);
      *(bf16x4*)(outp + 32 + j2 * 8 + hi * 4) = ov;
    }
  }
#undef STAGE
}

// ---------------- launch ----------------
extern "C" void kernel_launch(void* const* d_in, const int* in_sizes, int n_in,
                              void* d_out, int out_size, void* d_ws, size_t ws_size,
                              hipStream_t stream) {
  (void)in_sizes; (void)n_in; (void)out_size; (void)ws_size;
  const float* x    = (const float*)d_in[0];
  const float* p    = (const float*)d_in[1];
  const float* Wqkv = (const float*)d_in[2];
  const float* bqkv = (const float*)d_in[3];
  const float* Wout = (const float*)d_in[4];
  const float* bout = (const float*)d_in[5];
  const float* proj = (const float*)d_in[6];
  float* out = (float*)d_out;

  char* ws = (char*)d_ws;
  size_t off = 0;
  bf16* xb     = (bf16*)(ws + off); off += (size_t)4096 * 1024 * 2;
  bf16* pb     = (bf16*)(ws + off); off += (size_t)4096 * 1024 * 2;
  bf16* WqkvT  = (bf16*)(ws + off); off += (size_t)3072 * 1024 * 2;
  bf16* projT  = (bf16*)(ws + off); off += (size_t)512  * 1024 * 2;
  bf16* WoutT  = (bf16*)(ws + off); off += (size_t)1024 * 1024 * 2;
  float* phases= (float*)(ws + off); off += (size_t)4096 * 512 * 4;
  bf16* qb     = (bf16*)(ws + off); off += (size_t)4096 * 1024 * 2;
  bf16* kb     = (bf16*)(ws + off); off += (size_t)4096 * 1024 * 2;
  bf16* vb     = (bf16*)(ws + off); off += (size_t)4096 * 1024 * 2;
  bf16* attnb  = (bf16*)(ws + off); off += (size_t)4096 * 1024 * 2;

  k_convert<<<4096, 256, 0, stream>>>(x, xb, 1048576);
  k_convert<<<4096, 256, 0, stream>>>(p, pb, 1048576);
  k_transpose<<<dim3(48, 16), 256, 0, stream>>>(Wqkv, WqkvT, 1024, 3072);
  k_transpose<<<dim3(8, 16),  256, 0, stream>>>(proj, projT, 1024, 512);
  k_transpose<<<dim3(16, 16), 256, 0, stream>>>(Wout, WoutT, 1024, 1024);

  k_gemm128<<<dim3(32, 4), 256, 0, stream>>>(pb, projT, nullptr, phases, 4096, 512, 1024);
  k_gemm_qkv<<<dim3(32, 24), 256, 0, stream>>>(xb, WqkvT, bqkv, phases, qb, kb, vb);

  k_flash_attn5<<<1024, 256, 0, stream>>>(qb, kb, vb, attnb);

  k_gemm128<<<dim3(32, 8), 256, 0, stream>>>(attnb, WoutT, bout, out, 4096, 1024, 1024);
}